// Round 5
// baseline (92.970 us; speedup 1.0000x reference)
//
#include <hip/hip_runtime.h>

#define THREADS 512

#define IN_C 32
#define OUT_C 64
#define HW 64
#define Q_N 36
#define P_N 8
#define MB 8

#define SXW 66                      // cols -1..64
#define SXPL (3 * SXW)              // per-channel plane: 3 rows x 66
#define SXSZ (IN_C * SXPL)          // 6336 floats = 25.3 KB

__global__ __launch_bounds__(THREADS, 4)
void morr_conv_kernel(const float* __restrict__ x,
                      const float* __restrict__ weight,
                      const float* __restrict__ mos,
                      float* __restrict__ out)
{
    __shared__ float sx[SXSZ];
    __shared__ float slds[Q_N];

    const int tid = threadIdx.x;
    const int blk = blockIdx.x;
    const int b   = blk >> 6;        // image
    const int row = blk & 63;        // output row

    // gain (100/36 on x^2) folded with 1/(2*pi): phases come out in revolutions
    const float GI = 1.6666666666666667f * 0.15915494309189535f;

    // tr = (S-c)/(D-c) = 1 + E/(D-c), c = C2*cos(phi); sum_q sc_q = 0 (Q even)
    // => out = sum_q (sc_q*E) * rcp(D - c)
    const float A_ = 0.8578f, R_ = 0.8985f;
    const float S_ = A_ * A_ + R_ * R_;
    const float D_ = 1.f + (A_ * R_) * (A_ * R_);
    const float C2 = 2.f * A_ * R_;
    const float E_ = S_ - D_;

    // ---- stage squared, scaled inputs: rows row-1..row+1, cols -1..64 ----
    for (int idx = tid; idx < SXSZ; idx += THREADS) {
        int c    = idx / SXPL;
        int rem  = idx - c * SXPL;
        int r    = rem / SXW;
        int col  = rem - r * SXW;
        int gh = row + r - 1;
        int gw = col - 1;
        float v = 0.f;
        if ((unsigned)gh < 64u && (unsigned)gw < 64u)
            v = x[((b * IN_C + c) * HW + gh) * HW + gw];
        sx[idx] = GI * v * v;
    }
    // ---- signed scale with E folded ----
    if (tid < Q_N)
        slds[tid] = ((tid < 18) ? mos[tid] : -mos[tid - 18]) * E_;
    __syncthreads();

    const int px = tid & 63;                                   // pixel col
    const int p  = __builtin_amdgcn_readfirstlane(tid >> 6);   // wave-uniform p
    const float* __restrict__ wp = weight + p * (Q_N * MB);    // SGPR base

    float acc[8];
#pragma unroll
    for (int i = 0; i < 8; ++i) acc[i] = 0.f;

#pragma unroll 1
    for (int z = 0; z < 4; ++z) {
        const int sbase = (z * 8) * SXPL + px;
        const int qz = z * 9;
        const float* __restrict__ wpz = wp + z * 9 * MB;       // uniform
#pragma unroll
        for (int qi = 0; qi < 9; ++qi) {
            // im2col gather: u = qi*8+j in [0,72) compile-time; one base + imm offs
            float iv[8];
#pragma unroll
            for (int j = 0; j < 8; ++j) {
                const int u  = qi * 8 + j;
                const int cu = u / 9;
                const int r  = u - cu * 9;
                const int ki = r / 3;
                const int kj = r - ki * 3;
                iv[j] = sx[sbase + cu * SXPL + ki * SXW + kj];
            }
            // wave-uniform weights -> scalar loads, compile-time offsets
            float wv[8];
#pragma unroll
            for (int m = 0; m < 8; ++m) wv[m] = wpz[qi * MB + m];

            float ph[8];
#pragma unroll
            for (int k = 0; k < 8; ++k) ph[k] = iv[0] * wv[k];
#pragma unroll
            for (int j = 1; j < 8; ++j) {
#pragma unroll
                for (int k = 0; k < 8; ++k)
                    ph[k] = fmaf(iv[j], wv[(k - j) & 7], ph[k]);
            }
            const float sc = slds[qz + qi];                    // uniform broadcast
#pragma unroll
            for (int k = 0; k < 8; ++k) {
                float cc = __builtin_amdgcn_cosf(ph[k]);       // revolutions
                float d  = fmaf(-C2, cc, D_);
                acc[k] = fmaf(sc, __builtin_amdgcn_rcpf(d), acc[k]);
            }
        }
    }

    // ---- store: oc = p*8+k; 64 contiguous floats per wave per k ----
    float* op = out + ((b * OUT_C + p * MB) * (HW * HW)) + row * HW + px;
#pragma unroll
    for (int k = 0; k < 8; ++k)
        op[k * (HW * HW)] = acc[k];
}

extern "C" void kernel_launch(void* const* d_in, const int* in_sizes, int n_in,
                              void* d_out, int out_size, void* d_ws, size_t ws_size,
                              hipStream_t stream) {
    const float* x      = (const float*)d_in[0];
    const float* weight = (const float*)d_in[1];
    const float* mos    = (const float*)d_in[2];
    float* out = (float*)d_out;

    // 8 images x 64 rows; block = 8 waves (one p each) x 64-pixel row
    dim3 grid(512), block(THREADS);
    hipLaunchKernelGGL(morr_conv_kernel, grid, block, 0, stream, x, weight, mos, out);
}

// Round 7
// 90.025 us; speedup vs baseline: 1.0327x; 1.0327x over previous
//
#include <hip/hip_runtime.h>

#define THREADS 1024

#define IN_C 32
#define OUT_C 64
#define HW 64
#define Q_N 36
#define P_N 8
#define MB 8

#define SXW 66                      // cols -1..64
#define SXPL (3 * SXW)              // per-channel plane: 3 rows x 66
#define SXSZ (IN_C * SXPL)          // 6336 floats = 25.3 KB

__global__ __launch_bounds__(THREADS, 8)
void morr_conv_kernel(const float* __restrict__ x,
                      const float* __restrict__ weight,
                      const float* __restrict__ mos,
                      float* __restrict__ out)
{
    __shared__ float sx[SXSZ];
    __shared__ float slds[Q_N];
    __shared__ float red[P_N * MB * 64];   // 4096 floats = 16 KB

    const int tid = threadIdx.x;
    const int blk = blockIdx.x;
    const int b   = blk >> 6;        // image
    const int row = blk & 63;        // output row

    // gain (100/36 on x^2) folded with 1/(2*pi): phases in revolutions
    const float GI = 1.6666666666666667f * 0.15915494309189535f;

    // tr = (S-c)/(D-c) = 1 + E/(D-c), c = C2*cos(phi); sum_q sc_q = 0 (Q even)
    // => out = sum_q (sc_q*E) * rcp(D - c)
    const float A_ = 0.8578f, R_ = 0.8985f;
    const float S_ = A_ * A_ + R_ * R_;
    const float D_ = 1.f + (A_ * R_) * (A_ * R_);
    const float C2 = 2.f * A_ * R_;
    const float E_ = S_ - D_;

    // ---- stage squared, scaled inputs: rows row-1..row+1, cols -1..64 ----
    for (int idx = tid; idx < SXSZ; idx += THREADS) {
        int c    = idx / SXPL;
        int rem  = idx - c * SXPL;
        int r    = rem / SXW;
        int col  = rem - r * SXW;
        int gh = row + r - 1;
        int gw = col - 1;
        float v = 0.f;
        if ((unsigned)gh < 64u && (unsigned)gw < 64u)
            v = x[((b * IN_C + c) * HW + gh) * HW + gw];
        sx[idx] = GI * v * v;
    }
    // ---- signed scale with E folded ----
    if (tid < Q_N)
        slds[tid] = ((tid < 18) ? mos[tid] : -mos[tid - 18]) * E_;
    __syncthreads();

    const int px = tid & 63;                                        // pixel col
    const int wv_id = tid >> 6;                                     // wave 0..15
    const int p  = __builtin_amdgcn_readfirstlane(wv_id & 7);       // wave-uniform
    const int qh = __builtin_amdgcn_readfirstlane(wv_id >> 3);      // q-half 0/1
    const float* __restrict__ wp = weight + p * (Q_N * MB);

    float acc[8];
#pragma unroll
    for (int i = 0; i < 8; ++i) acc[i] = 0.f;

#pragma unroll 1
    for (int z = 2 * qh; z < 2 * qh + 2; ++z) {
        const int sbase = (z * 8) * SXPL + px;
        const int qz = z * 9;
        const float* __restrict__ wpz = wp + z * 9 * MB;   // uniform
#pragma unroll
        for (int qi = 0; qi < 9; ++qi) {
            // im2col gather: u = qi*8+j in [0,72) compile-time offsets
            float iv[8];
#pragma unroll
            for (int j = 0; j < 8; ++j) {
                const int u  = qi * 8 + j;
                const int cu = u / 9;
                const int r  = u - cu * 9;
                const int ki = r / 3;
                const int kj = r - ki * 3;
                iv[j] = sx[sbase + cu * SXPL + ki * SXW + kj];
            }
            // wave-uniform weights -> scalar loads
            float wvv[8];
#pragma unroll
            for (int m = 0; m < 8; ++m) wvv[m] = wpz[qi * MB + m];

            float ph[8];
#pragma unroll
            for (int k = 0; k < 8; ++k) ph[k] = iv[0] * wvv[k];
#pragma unroll
            for (int j = 1; j < 8; ++j) {
#pragma unroll
                for (int k = 0; k < 8; ++k)
                    ph[k] = fmaf(iv[j], wvv[(k - j) & 7], ph[k]);
            }
            const float sc = slds[qz + qi];                // uniform broadcast
#pragma unroll
            for (int k = 0; k < 8; ++k) {
                float cc = __builtin_amdgcn_cosf(ph[k]);   // revolutions
                float d  = fmaf(-C2, cc, D_);
                acc[k] = fmaf(sc, __builtin_amdgcn_rcpf(d), acc[k]);
            }
        }
    }

    // ---- cross-wave q reduction: qh=1 dumps, qh=0 adds + stores ----
    __syncthreads();
    if (qh == 1) {
#pragma unroll
        for (int k = 0; k < 8; ++k)
            red[(p * MB + k) * 64 + px] = acc[k];
    }
    __syncthreads();
    if (qh == 0) {
        float* op = out + ((b * OUT_C + p * MB) * (HW * HW)) + row * HW + px;
#pragma unroll
        for (int k = 0; k < 8; ++k)
            op[k * (HW * HW)] = acc[k] + red[(p * MB + k) * 64 + px];
    }
}

extern "C" void kernel_launch(void* const* d_in, const int* in_sizes, int n_in,
                              void* d_out, int out_size, void* d_ws, size_t ws_size,
                              hipStream_t stream) {
    const float* x      = (const float*)d_in[0];
    const float* weight = (const float*)d_in[1];
    const float* mos    = (const float*)d_in[2];
    float* out = (float*)d_out;

    // 8 images x 64 rows; block = 16 waves: (p 0..7) x (q-half 0..1)
    dim3 grid(512), block(THREADS);
    hipLaunchKernelGGL(morr_conv_kernel, grid, block, 0, stream, x, weight, mos, out);
}

// Round 8
// 86.062 us; speedup vs baseline: 1.0803x; 1.0460x over previous
//
#include <hip/hip_runtime.h>

#define THREADS 512

#define IN_C 32
#define HW 64
#define Q_N 36

typedef float f32x4 __attribute__((ext_vector_type(4)));
typedef short s16x8 __attribute__((ext_vector_type(8)));

// LDS layout (bytes):
//  AIM [64 px][296 u] bf16  : 0      .. 37888    (im2col, row stride 592B, 16B-aligned)
//  WB  [36 q][4 mt][16][8]  : 37888  .. 74752    (circulant-expanded weights, bf16)
//  ZB  zero block (512B)    : 74752  .. 75264
//  SC  scale f32[36]        : 75264  .. 75408
#define AIM_OFF 0
#define WB_OFF  37888
#define ZB_OFF  74752
#define SC_OFF  75264
#define LDS_BYTES 75424

__device__ __forceinline__ unsigned short f2bf(float f) {
    union { float f; unsigned int u; } v; v.f = f;
    unsigned int t = v.u + 0x7FFFu + ((v.u >> 16) & 1u);   // round-to-nearest-even
    return (unsigned short)(t >> 16);
}

__global__ __launch_bounds__(THREADS, 4)
void morr_conv_kernel(const float* __restrict__ x,
                      const float* __restrict__ weight,
                      const float* __restrict__ mos,
                      float* __restrict__ out)
{
    __shared__ __align__(16) unsigned char lds[LDS_BYTES];
    unsigned short* Aim = (unsigned short*)(lds + AIM_OFF);
    unsigned short* Wb  = (unsigned short*)(lds + WB_OFF);
    float* scl          = (float*)(lds + SC_OFF);

    const int tid = threadIdx.x;
    const int blk = blockIdx.x;
    const int b   = blk >> 6;        // image
    const int row = blk & 63;        // output row

    // MORR_GAIN (10/6) folded with 1/(2*pi): phase comes out in revolutions
    const float GI = 1.6666666666666667f * 0.15915494309189535f;
    const float A_ = 0.8578f, R_ = 0.8985f;
    const float S_ = A_ * A_ + R_ * R_;
    const float D_ = 1.f + (A_ * R_) * (A_ * R_);
    const float C2 = 2.f * A_ * R_;
    const float E_ = S_ - D_;        // tr = 1 + E/(D-c); sum_q sc_q = 0 kills the 1

    // ---- stage im2col bf16: Aim[px][u], u = c*9 + ki*3 + kj ----
    {
        const int px = tid & 63;
        const int g  = tid >> 6;
#pragma unroll
        for (int c2 = 0; c2 < 4; ++c2) {
            const int c = g * 4 + c2;
            const float* xc = x + ((b * IN_C + c) * HW) * HW;
#pragma unroll
            for (int ki = 0; ki < 3; ++ki) {
                const int gh = row + ki - 1;
                const bool rok = (unsigned)gh < 64u;
#pragma unroll
                for (int kj = 0; kj < 3; ++kj) {
                    const int gw = px + kj - 1;
                    float v = (rok && (unsigned)gw < 64u) ? xc[gh * HW + gw] : 0.f;
                    Aim[px * 296 + c * 9 + ki * 3 + kj] = f2bf(GI * v * v);
                }
            }
        }
    }
    // ---- stage circulant weights: Wb[((q*4+mt)*16+pr)*8+j] = w[p][q][(k-j)&7] ----
#pragma unroll
    for (int i = 0; i < 36; ++i) {
        const int idx = tid + 512 * i;
        const int q  = idx >> 9;
        const int mt = (idx >> 7) & 3;
        const int pr = (idx >> 3) & 15;
        const int j  = idx & 7;
        const int pk = mt * 16 + pr;
        const int p  = pk >> 3, k = pk & 7;
        Wb[idx] = f2bf(weight[p * 288 + q * 8 + ((k - j) & 7)]);
    }
    // ---- zero block + signed scale (E folded) ----
    if (tid < 256) ((unsigned short*)(lds + ZB_OFF))[tid] = 0;
    if (tid < Q_N) scl[tid] = ((tid < 18) ? mos[tid] : -mos[tid - 18]) * E_;
    __syncthreads();

    const int wv = tid >> 6;         // wave 0..7
    const int l  = tid & 63;
    const int ll = l & 15;
    const int lh = l >> 4;
    const int nt = wv & 3;           // px tile (N)
    const int m0 = (wv >> 2) * 2;    // first of 2 pk tiles (M)

    // B (im2col) fragment: lane holds u = q*8..q*8+7 at px = nt*16+ll (lh broadcast)
    const unsigned short* bB = Aim + (nt * 16 + ll) * 296;
    // A (weights) fragment: lanes l<16 real, l>=16 -> zero block (kills K-slots 8..31)
    const unsigned short* aW = (l < 16)
        ? (Wb + (m0 * 16 + ll) * 8)
        : (const unsigned short*)(lds + ZB_OFF);
    const int qstep = (l < 16) ? 512 : 0;   // ushorts per q (4 mt * 16 * 8)

    float acc[8];
#pragma unroll
    for (int i = 0; i < 8; ++i) acc[i] = 0.f;

    const f32x4 cz = {0.f, 0.f, 0.f, 0.f};

#pragma unroll
    for (int q = 0; q < Q_N; ++q) {
        s16x8 bfrag = *(const s16x8*)(bB + q * 8);
        s16x8 a0 = *(const s16x8*)(aW);
        s16x8 a1 = *(const s16x8*)(aW + 128);   // second mt tile (+256B; zero lanes stay in ZB)
        f32x4 d0 = __builtin_amdgcn_mfma_f32_16x16x32_bf16(a0, bfrag, cz, 0, 0, 0);
        f32x4 d1 = __builtin_amdgcn_mfma_f32_16x16x32_bf16(a1, bfrag, cz, 0, 0, 0);
        const float sc = scl[q];
#pragma unroll
        for (int r = 0; r < 4; ++r) {
            float c0 = __builtin_amdgcn_cosf(d0[r]);          // revolutions
            acc[r]     = fmaf(sc, __builtin_amdgcn_rcpf(fmaf(-C2, c0, D_)), acc[r]);
            float c1 = __builtin_amdgcn_cosf(d1[r]);
            acc[4 + r] = fmaf(sc, __builtin_amdgcn_rcpf(fmaf(-C2, c1, D_)), acc[4 + r]);
        }
        aW += qstep;
    }

    // ---- store: D layout col=l&15 (px), row=(l>>4)*4+r (pk within tile) ----
    const int col = nt * 16 + ll;
#pragma unroll
    for (int t = 0; t < 2; ++t) {
#pragma unroll
        for (int r = 0; r < 4; ++r) {
            const int pk = (m0 + t) * 16 + lh * 4 + r;
            out[(b * 64 + pk) * (HW * HW) + row * HW + col] = acc[t * 4 + r];
        }
    }
}

extern "C" void kernel_launch(void* const* d_in, const int* in_sizes, int n_in,
                              void* d_out, int out_size, void* d_ws, size_t ws_size,
                              hipStream_t stream) {
    const float* x      = (const float*)d_in[0];
    const float* weight = (const float*)d_in[1];
    const float* mos    = (const float*)d_in[2];
    float* out = (float*)d_out;

    // 8 images x 64 rows; block = 8 waves (4 px-tiles x 2 pk-tile-pairs)
    dim3 grid(512), block(THREADS);
    hipLaunchKernelGGL(morr_conv_kernel, grid, block, 0, stream, x, weight, mos, out);
}

// Round 9
// 83.499 us; speedup vs baseline: 1.1134x; 1.0307x over previous
//
#include <hip/hip_runtime.h>

#define IN_C 32
#define HW 64
#define Q_N 36

typedef float f32x4 __attribute__((ext_vector_type(4)));
typedef short s16x8 __attribute__((ext_vector_type(8)));
typedef short s16x4 __attribute__((ext_vector_type(4)));

// workspace layout (bytes)
#define WEXP_OFF 0          // [36 q][4 mt][16 pr][8 j] bf16 = 73728 B
#define ZW_OFF   73728      // 512 B zeros (K-padding for lanes l>=16)
#define SCL_OFF  74240      // f32[36] signed scale * E
#define GX2_OFF  75776      // bf16 GI*x^2, [8][32][64][64] = 2097152 B

__device__ __forceinline__ unsigned short f2bf(float f) {
    union { float f; unsigned int u; } v; v.f = f;
    unsigned int t = v.u + 0x7FFFu + ((v.u >> 16) & 1u);   // RNE
    return (unsigned short)(t >> 16);
}

// tr algebra constants
#define A_C 0.8578f
#define R_C 0.8985f
#define S_C (A_C*A_C + R_C*R_C)
#define D_C (1.f + (A_C*R_C)*(A_C*R_C))
#define C2_C (2.f*A_C*R_C)
#define E_C (S_C - D_C)
// MORR_GAIN (10/6) folded with 1/(2*pi): phases in revolutions
#define GI_C (1.6666666666666667f * 0.15915494309189535f)

__global__ __launch_bounds__(512)
void morr_pre(const float* __restrict__ x,
              const float* __restrict__ weight,
              const float* __restrict__ mos,
              unsigned char* __restrict__ ws)
{
    const int tid = threadIdx.x;
    const int blk = blockIdx.x;
    if (blk < 512) {
        // gx2: 1048576 elems, 4 per thread
        const int i = (blk * 512 + tid) * 4;
        float4 v = *(const float4*)(x + i);
        unsigned short o0 = f2bf(GI_C * v.x * v.x);
        unsigned short o1 = f2bf(GI_C * v.y * v.y);
        unsigned short o2 = f2bf(GI_C * v.z * v.z);
        unsigned short o3 = f2bf(GI_C * v.w * v.w);
        s16x4 o = {(short)o0, (short)o1, (short)o2, (short)o3};
        *(s16x4*)(ws + GX2_OFF + (size_t)i * 2) = o;
    } else {
        // circulant-expanded weights: [q][mt][16][8], 36864 elems, 72/thread
        unsigned short* wexp = (unsigned short*)(ws + WEXP_OFF);
#pragma unroll
        for (int it = 0; it < 72; ++it) {
            const int idx = tid + 512 * it;
            const int q  = idx >> 9;
            const int mt = (idx >> 7) & 3;
            const int pr = (idx >> 3) & 15;
            const int j  = idx & 7;
            const int pk = mt * 16 + pr;
            const int p  = pk >> 3, k = pk & 7;
            wexp[idx] = f2bf(weight[p * 288 + q * 8 + ((k - j) & 7)]);
        }
        if (tid < 128) ((float*)(ws + ZW_OFF))[tid] = 0.f;
        if (tid < Q_N)
            ((float*)(ws + SCL_OFF))[tid] =
                ((tid < 18) ? mos[tid] : -mos[tid - 18]) * E_C;
    }
}

__global__ __launch_bounds__(512, 4)
void morr_conv_kernel(const unsigned char* __restrict__ ws,
                      float* __restrict__ out)
{
    __shared__ __align__(16) unsigned short Aim[64 * 296];   // im2col, 37888 B

    const int tid = threadIdx.x;
    const int blk = blockIdx.x;
    const int b   = blk >> 6;        // image
    const int row = blk & 63;        // output row

    const unsigned short* gx2 = (const unsigned short*)(ws + GX2_OFF);

    // ---- stage im2col: thread (px, g) owns u in [36g, 36g+36) = channels 4g..4g+3 ----
    {
        const int px = tid & 63;
        const int g  = tid >> 6;
        unsigned short buf[36];
#pragma unroll
        for (int cc = 0; cc < 4; ++cc) {
            const int c = g * 4 + cc;
            const unsigned short* xc = gx2 + ((b * IN_C + c) << 12);
#pragma unroll
            for (int ki = 0; ki < 3; ++ki) {
                const int gh = row + ki - 1;
                const bool rok = (unsigned)gh < 64u;
#pragma unroll
                for (int kj = 0; kj < 3; ++kj) {
                    const int gw = px + kj - 1;
                    unsigned short v = 0;
                    if (rok && (unsigned)gw < 64u) v = xc[(gh << 6) + gw];
                    buf[cc * 9 + ki * 3 + kj] = v;
                }
            }
        }
        unsigned short* dst = Aim + px * 296 + g * 36;   // byte 592*px+72*g: 8-aligned
#pragma unroll
        for (int i = 0; i < 9; ++i) {
            s16x4 v = {(short)buf[i*4], (short)buf[i*4+1],
                       (short)buf[i*4+2], (short)buf[i*4+3]};
            *(s16x4*)(dst + i * 4) = v;
        }
    }
    __syncthreads();

    const int wv = tid >> 6;         // wave 0..7
    const int l  = tid & 63;
    const int ll = l & 15;
    const int lh = l >> 4;
    const int nt = wv & 3;           // px tile (N)
    const int m0 = (wv >> 2) * 2;    // first of 2 pk tiles (M)

    // B (im2col) fragment base: lane holds u = q*8..q*8+7 at px = nt*16+ll
    const unsigned short* bB = Aim + (nt * 16 + ll) * 296;
    // A (weights) from GLOBAL (pre-expanded, L2-hot); lanes l>=16 -> zero block
    const unsigned short* aW;
    int qs;
    if (l < 16) { aW = (const unsigned short*)(ws + WEXP_OFF) + (m0 * 16 + ll) * 8; qs = 512; }
    else        { aW = (const unsigned short*)(ws + ZW_OFF);                        qs = 0;   }
    const float* __restrict__ sp = (const float*)(ws + SCL_OFF);   // uniform -> s_load

    float acc[8];
#pragma unroll
    for (int i = 0; i < 8; ++i) acc[i] = 0.f;

    const f32x4 cz = {0.f, 0.f, 0.f, 0.f};

#pragma unroll
    for (int q = 0; q < Q_N; ++q) {
        s16x8 bfrag = *(const s16x8*)(bB + q * 8);
        s16x8 a0 = *(const s16x8*)(aW + q * qs);
        s16x8 a1 = *(const s16x8*)(aW + q * qs + 128);   // second mt tile (+256 B)
        f32x4 d0 = __builtin_amdgcn_mfma_f32_16x16x32_bf16(a0, bfrag, cz, 0, 0, 0);
        f32x4 d1 = __builtin_amdgcn_mfma_f32_16x16x32_bf16(a1, bfrag, cz, 0, 0, 0);
        const float sc = sp[q];
#pragma unroll
        for (int r = 0; r < 4; ++r) {
            float c0 = __builtin_amdgcn_cosf(d0[r]);          // revolutions
            acc[r]     = fmaf(sc, __builtin_amdgcn_rcpf(fmaf(-C2_C, c0, D_C)), acc[r]);
            float c1 = __builtin_amdgcn_cosf(d1[r]);
            acc[4 + r] = fmaf(sc, __builtin_amdgcn_rcpf(fmaf(-C2_C, c1, D_C)), acc[4 + r]);
        }
    }

    // ---- store: D layout col=l&15 (px), row=(l>>4)*4+r (pk within tile) ----
    const int col = nt * 16 + ll;
#pragma unroll
    for (int t = 0; t < 2; ++t) {
#pragma unroll
        for (int r = 0; r < 4; ++r) {
            const int pk = (m0 + t) * 16 + lh * 4 + r;
            out[(b * 64 + pk) * (HW * HW) + row * HW + col] = acc[t * 4 + r];
        }
    }
}

extern "C" void kernel_launch(void* const* d_in, const int* in_sizes, int n_in,
                              void* d_out, int out_size, void* d_ws, size_t ws_size,
                              hipStream_t stream) {
    const float* x      = (const float*)d_in[0];
    const float* weight = (const float*)d_in[1];
    const float* mos    = (const float*)d_in[2];
    float* out = (float*)d_out;
    unsigned char* ws = (unsigned char*)d_ws;

    hipLaunchKernelGGL(morr_pre, dim3(513), dim3(512), 0, stream, x, weight, mos, ws);
    hipLaunchKernelGGL(morr_conv_kernel, dim3(512), dim3(512), 0, stream, ws, out);
}